// Round 1
// baseline (631.004 us; speedup 1.0000x reference)
//
#include <hip/hip_runtime.h>

// ---------------------------------------------------------------------------
// MultimodalFusion: 6 GEMMs (fp16 MFMA, f32 accum) + RPB weight preprocessing
// ws layout (~218 MB): fp16 copies of activations/weights, concat/routed/h|g
// ---------------------------------------------------------------------------

typedef _Float16 f16x8 __attribute__((ext_vector_type(8)));
typedef float f32x4 __attribute__((ext_vector_type(4)));

__device__ __forceinline__ unsigned short f16b(float v) {
  union { _Float16 h; unsigned short u; } cv; cv.h = (_Float16)v; return cv.u;
}

__device__ __forceinline__ void load_lds16(const void* g, void* l) {
  __builtin_amdgcn_global_load_lds(
      (const __attribute__((address_space(1))) void*)g,
      (__attribute__((address_space(3))) void*)l, 16, 0, 0);
}

__device__ __forceinline__ float sigmoidf_dev(float x) {
  return 1.0f / (1.0f + expf(-x));
}

// ---------------- preprocessing: f32 -> f16 conversion ----------------------
__global__ void f2h(const float* __restrict__ in, unsigned short* __restrict__ out, long n) {
  long n4 = n >> 2;
  for (long i = (long)blockIdx.x * blockDim.x + threadIdx.x; i < n4;
       i += (long)gridDim.x * blockDim.x) {
    float4 v = ((const float4*)in)[i];
    ushort4 o;
    o.x = f16b(v.x); o.y = f16b(v.y); o.z = f16b(v.z); o.w = f16b(v.w);
    ((ushort4*)out)[i] = o;
  }
}

// Wf2 * (1-mix) into W2[:, col0:col0+cols]
__global__ void conv_scaled(const float* __restrict__ W, int rows, int cols,
                            const float* __restrict__ mixp,
                            unsigned short* __restrict__ out, int ldd, int col0) {
  float s = 1.0f - sigmoidf_dev(mixp[0]);
  long S = (long)rows * cols;
  for (long i = (long)blockIdx.x * blockDim.x + threadIdx.x; i < S;
       i += (long)gridDim.x * blockDim.x) {
    int r = (int)(i / cols), c = (int)(i % cols);
    out[(long)r * ldd + col0 + c] = f16b(s * W[i]);
  }
}

__global__ void mk_bias2(const float* __restrict__ bq2, const float* __restrict__ bf2,
                         const float* __restrict__ mixp, float* __restrict__ b2, int n) {
  int i = blockIdx.x * blockDim.x + threadIdx.x;
  if (i < n) {
    float mix = sigmoidf_dev(mixp[0]);
    b2[i] = mix * bq2[i] + (1.0f - mix) * bf2[i];
  }
}

// ---------------- RPB stats: deterministic reductions -----------------------
__global__ void part_abssum(const float4* __restrict__ W4, long n4, float* __restrict__ part) {
  __shared__ float s[256];
  float acc = 0.f;
  for (long i = (long)blockIdx.x * blockDim.x + threadIdx.x; i < n4;
       i += (long)gridDim.x * blockDim.x) {
    float4 v = W4[i];
    acc += fabsf(v.x) + fabsf(v.y) + fabsf(v.z) + fabsf(v.w);
  }
  s[threadIdx.x] = acc; __syncthreads();
  for (int o = 128; o > 0; o >>= 1) {
    if ((int)threadIdx.x < o) s[threadIdx.x] += s[threadIdx.x + o];
    __syncthreads();
  }
  if (threadIdx.x == 0) part[blockIdx.x] = s[0];
}

__global__ void fin_abssum(const float* __restrict__ part, int np, long S,
                           float* __restrict__ scal) {
  __shared__ float s[256];
  float a = 0.f;
  for (int i = threadIdx.x; i < np; i += 256) a += part[i];
  s[threadIdx.x] = a; __syncthreads();
  for (int o = 128; o > 0; o >>= 1) {
    if ((int)threadIdx.x < o) s[threadIdx.x] += s[threadIdx.x + o];
    __syncthreads();
  }
  if (threadIdx.x == 0) scal[0] = 0.7f * (s[0] / (float)S);  // delta
}

__global__ void part_kept(const float* __restrict__ W, long S, const float* __restrict__ scal,
                          float* __restrict__ pb, unsigned* __restrict__ pc) {
  __shared__ float sf[256]; __shared__ unsigned sc[256];
  float delta = scal[0];
  float a = 0.f; unsigned c = 0;
  for (long i = (long)blockIdx.x * blockDim.x + threadIdx.x; i < S;
       i += (long)gridDim.x * blockDim.x) {
    float aw = fabsf(W[i]);
    if (aw > delta) { a += aw; ++c; }
  }
  sf[threadIdx.x] = a; sc[threadIdx.x] = c; __syncthreads();
  for (int o = 128; o > 0; o >>= 1) {
    if ((int)threadIdx.x < o) { sf[threadIdx.x] += sf[threadIdx.x + o]; sc[threadIdx.x] += sc[threadIdx.x + o]; }
    __syncthreads();
  }
  if (threadIdx.x == 0) { pb[blockIdx.x] = sf[0]; pc[blockIdx.x] = sc[0]; }
}

__global__ void fin_kept(const float* __restrict__ pb, const unsigned* __restrict__ pc, int np,
                         float* __restrict__ scal, unsigned* __restrict__ u, unsigned k,
                         unsigned* __restrict__ hist) {
  __shared__ float sf[256]; __shared__ unsigned sc[256];
  float a = 0.f; unsigned c = 0;
  for (int i = threadIdx.x; i < np; i += 256) { a += pb[i]; c += pc[i]; }
  sf[threadIdx.x] = a; sc[threadIdx.x] = c; __syncthreads();
  for (int o = 128; o > 0; o >>= 1) {
    if ((int)threadIdx.x < o) { sf[threadIdx.x] += sf[threadIdx.x + o]; sc[threadIdx.x] += sc[threadIdx.x + o]; }
    __syncthreads();
  }
  if (threadIdx.x == 0) {
    float cnt = (float)sc[0]; if (cnt < 1.f) cnt = 1.f;
    scal[1] = sf[0] / cnt;  // alpha
    u[0] = 0;               // prefix
    u[1] = k;               // k remaining
  }
  hist[threadIdx.x] = 0;
}

// ---------------- radix select of kth largest |res| -------------------------
__global__ void hist_pass(const float* __restrict__ W, long S, const float* __restrict__ scal,
                          const unsigned* __restrict__ u, unsigned* __restrict__ hist, int shift) {
  __shared__ unsigned h[256];
  h[threadIdx.x] = 0; __syncthreads();
  float delta = scal[0], alpha = scal[1];
  unsigned prefix = u[0];
  int hs = shift + 8;
  for (long i = (long)blockIdx.x * blockDim.x + threadIdx.x; i < S;
       i += (long)gridDim.x * blockDim.x) {
    float w = W[i];
    float aw = fabsf(w);
    float wq = (aw > delta) ? copysignf(alpha, w) : 0.0f;
    unsigned ub = __float_as_uint(fabsf(w - wq));
    bool ok = (hs >= 32) || ((ub >> hs) == (prefix >> hs));
    if (ok) atomicAdd(&h[(ub >> shift) & 255u], 1u);
  }
  __syncthreads();
  if (h[threadIdx.x]) atomicAdd(&hist[threadIdx.x], h[threadIdx.x]);
}

__global__ void sel_pass(unsigned* __restrict__ hist, unsigned* __restrict__ u, int shift, int last) {
  __shared__ unsigned h[256];
  int t = threadIdx.x;
  h[t] = hist[t];
  __syncthreads();
  if (t == 0) {
    unsigned krem = u[1];
    unsigned cum = 0, above = 0;
    int bstar = 0;
    for (int b = 255; b >= 0; --b) {
      unsigned nc = cum + h[b];
      if (nc >= krem) { bstar = b; above = cum; break; }
      cum = nc;
    }
    u[0] |= ((unsigned)bstar) << shift;
    u[1] = krem - above;
    if (last) u[2] = u[0];  // kth value bit pattern
  }
  __syncthreads();
  hist[t] = 0;
}

// ---------------- RPB weight writers -----------------------------------------
__global__ void write_rpb(const float* __restrict__ W, long S, const float* __restrict__ scal,
                          const unsigned* __restrict__ u, unsigned short* __restrict__ out) {
  float delta = scal[0], alpha = scal[1];
  unsigned kth = u[2];
  for (long i = (long)blockIdx.x * blockDim.x + threadIdx.x; i < S;
       i += (long)gridDim.x * blockDim.x) {
    float w = W[i];
    float aw = fabsf(w);
    float wq = (aw > delta) ? copysignf(alpha, w) : 0.0f;
    float res = w - wq;
    unsigned ub = __float_as_uint(fabsf(res));
    float v = wq + ((ub >= kth) ? res : 0.0f);
    out[i] = f16b(v);
  }
}

__global__ void write_rpb_scaled(const float* __restrict__ W, int rows, int cols,
                                 const float* __restrict__ scal, const unsigned* __restrict__ u,
                                 const float* __restrict__ mixp,
                                 unsigned short* __restrict__ out, int ldd, int col0) {
  float delta = scal[0], alpha = scal[1];
  unsigned kth = u[2];
  float mix = sigmoidf_dev(mixp[0]);
  long S = (long)rows * cols;
  for (long i = (long)blockIdx.x * blockDim.x + threadIdx.x; i < S;
       i += (long)gridDim.x * blockDim.x) {
    int r = (int)(i / cols), c = (int)(i % cols);
    float w = W[i];
    float aw = fabsf(w);
    float wq = (aw > delta) ? copysignf(alpha, w) : 0.0f;
    float res = w - wq;
    unsigned ub = __float_as_uint(fabsf(res));
    float v = wq + ((ub >= kth) ? res : 0.0f);
    out[(long)r * ldd + col0 + c] = f16b(mix * v);
  }
}

// ---------------- GEMM: C[M,N] = A[M,K] @ B[N,K]^T + bias, fp16 MFMA ---------
// EPI 0: route (store concat f16 + routed f16), 1: relu (store f16), 2: f32 out
template <int EPI>
__global__ __launch_bounds__(256) void gemm_bt(
    const unsigned short* __restrict__ A, const unsigned short* __restrict__ Bw,
    const float* __restrict__ bias,
    unsigned short* __restrict__ o0, unsigned short* __restrict__ o1,
    float* __restrict__ oF, int K, int ldc, int col0) {
  __shared__ __align__(16) unsigned short lA[128 * 32];
  __shared__ __align__(16) unsigned short lB[128 * 32];
  const int tid = threadIdx.x;
  const int wid = tid >> 6;
  const int lane = tid & 63;
  const int wm = wid >> 1, wn = wid & 1;
  const long brow = (long)blockIdx.y * 128;
  const int bcol = blockIdx.x * 128;

  f32x4 acc[4][4];
#pragma unroll
  for (int i = 0; i < 4; ++i)
#pragma unroll
    for (int j = 0; j < 4; ++j)
#pragma unroll
      for (int e = 0; e < 4; ++e) acc[i][j][e] = 0.f;

  // staging: 8 KB per operand per K-step; per wave 2 issues x 1024 B (lane*16)
  const int o_0 = wid * 2048 + lane * 16;
  const int o_1 = o_0 + 1024;
  const int rS0 = o_0 >> 6, cS0 = (o_0 & 63) >> 1;
  const int rS1 = o_1 >> 6, cS1 = (o_1 & 63) >> 1;
  const unsigned short* gA0 = A + (brow + rS0) * K + cS0;
  const unsigned short* gA1 = A + (brow + rS1) * K + cS1;
  const unsigned short* gB0 = Bw + (long)(bcol + rS0) * K + cS0;
  const unsigned short* gB1 = Bw + (long)(bcol + rS1) * K + cS1;
  unsigned short* lAb0 = lA + wid * 1024;
  unsigned short* lAb1 = lA + wid * 1024 + 512;
  unsigned short* lBb0 = lB + wid * 1024;
  unsigned short* lBb1 = lB + wid * 1024 + 512;

  const int kb = (lane >> 4) * 16;  // k byte offset of this lane's fragment
  const int rAf = wm * 64 + (lane & 15);
  const int rBf = wn * 64 + (lane & 15);

  for (int k0 = 0; k0 < K; k0 += 32) {
    load_lds16(gA0 + k0, lAb0);
    load_lds16(gA1 + k0, lAb1);
    load_lds16(gB0 + k0, lBb0);
    load_lds16(gB1 + k0, lBb1);
    __syncthreads();
    f16x8 af[4], bfr[4];
#pragma unroll
    for (int i = 0; i < 4; ++i) {
      af[i] = *(const f16x8*)((const char*)lA + (rAf + i * 16) * 64 + kb);
      bfr[i] = *(const f16x8*)((const char*)lB + (rBf + i * 16) * 64 + kb);
    }
#pragma unroll
    for (int i = 0; i < 4; ++i)
#pragma unroll
      for (int j = 0; j < 4; ++j)
        acc[i][j] = __builtin_amdgcn_mfma_f32_16x16x32_f16(af[i], bfr[j], acc[i][j], 0, 0, 0);
    __syncthreads();
  }

  // epilogue: C row = (lane>>4)*4 + e, col = lane&15 (verified m89 layout)
  const int c_base = bcol + wn * 64;
  const int r_base = (int)brow + wm * 64;
#pragma unroll
  for (int i = 0; i < 4; ++i) {
    int r0 = r_base + i * 16 + ((lane >> 4) << 2);
#pragma unroll
    for (int j = 0; j < 4; ++j) {
      int c = c_base + j * 16 + (lane & 15);
      float bb = bias[c];
#pragma unroll
      for (int e = 0; e < 4; ++e) {
        float v = acc[i][j][e] + bb;
        long idx = (long)(r0 + e) * ldc + col0 + c;
        if constexpr (EPI == 0) {
          o0[idx] = f16b(v);
          o1[idx] = f16b(fabsf(v) >= 0.05f ? v : 0.0f);
        } else if constexpr (EPI == 1) {
          o0[idx] = f16b(fmaxf(v, 0.0f));
        } else {
          oF[idx] = v;
        }
      }
    }
  }
}

// ---------------------------------------------------------------------------
extern "C" void kernel_launch(void* const* d_in, const int* in_sizes, int n_in,
                              void* d_out, int out_size, void* d_ws, size_t ws_size,
                              hipStream_t stream) {
  const float* xv = (const float*)d_in[0];
  const float* xt = (const float*)d_in[1];
  const float* xa = (const float*)d_in[2];
  const float* Wv = (const float*)d_in[3];
  const float* bv = (const float*)d_in[4];
  const float* Wt = (const float*)d_in[5];
  const float* bt = (const float*)d_in[6];
  const float* Wa = (const float*)d_in[7];
  const float* ba = (const float*)d_in[8];
  const float* Wq1 = (const float*)d_in[9];
  const float* bq1 = (const float*)d_in[10];
  const float* Wq2 = (const float*)d_in[11];
  const float* bq2 = (const float*)d_in[12];
  const float* Wf1 = (const float*)d_in[13];
  const float* bf1 = (const float*)d_in[14];
  const float* Wf2 = (const float*)d_in[15];
  const float* bf2 = (const float*)d_in[16];
  const float* mixp = (const float*)d_in[17];

  const int B = 8192, D = 1024, T = 3072;
  const int Kv = 2048, Kt = 1024, Ka = 512;

  char* w = (char*)d_ws;
  auto alloc = [&](size_t bytes) -> char* {
    char* p = w; w += (bytes + 255) & ~(size_t)255; return p;
  };
  unsigned short* xv_h = (unsigned short*)alloc((size_t)B * Kv * 2);
  unsigned short* xt_h = (unsigned short*)alloc((size_t)B * Kt * 2);
  unsigned short* xa_h = (unsigned short*)alloc((size_t)B * Ka * 2);
  unsigned short* wv_h = (unsigned short*)alloc((size_t)D * Kv * 2);
  unsigned short* wt_h = (unsigned short*)alloc((size_t)D * Kt * 2);
  unsigned short* wa_h = (unsigned short*)alloc((size_t)D * Ka * 2);
  unsigned short* wq1_h = (unsigned short*)alloc((size_t)D * T * 2);
  unsigned short* wf1_h = (unsigned short*)alloc((size_t)D * T * 2);
  unsigned short* w2_h = (unsigned short*)alloc((size_t)D * 2048 * 2);
  unsigned short* concat_h = (unsigned short*)alloc((size_t)B * T * 2);
  unsigned short* routed_h = (unsigned short*)alloc((size_t)B * T * 2);
  unsigned short* a2_h = (unsigned short*)alloc((size_t)B * 2048 * 2);
  float* b2 = (float*)alloc(D * 4);
  float* scal1 = (float*)alloc(64);
  unsigned* u1 = (unsigned*)alloc(64);
  unsigned* hist1 = (unsigned*)alloc(1024);
  float* pa1 = (float*)alloc(1024 * 4);
  float* pb1 = (float*)alloc(1024 * 4);
  unsigned* pc1 = (unsigned*)alloc(1024 * 4);
  float* scal2 = (float*)alloc(64);
  unsigned* u2 = (unsigned*)alloc(64);
  unsigned* hist2 = (unsigned*)alloc(1024);
  float* pa2 = (float*)alloc(1024 * 4);
  float* pb2 = (float*)alloc(1024 * 4);
  unsigned* pc2 = (unsigned*)alloc(1024 * 4);

  // ---- conversions to fp16 ----
  f2h<<<2048, 256, 0, stream>>>(xv, xv_h, (long)B * Kv);
  f2h<<<1024, 256, 0, stream>>>(xt, xt_h, (long)B * Kt);
  f2h<<<512, 256, 0, stream>>>(xa, xa_h, (long)B * Ka);
  f2h<<<256, 256, 0, stream>>>(Wv, wv_h, (long)D * Kv);
  f2h<<<128, 256, 0, stream>>>(Wt, wt_h, (long)D * Kt);
  f2h<<<64, 256, 0, stream>>>(Wa, wa_h, (long)D * Ka);
  f2h<<<512, 256, 0, stream>>>(Wf1, wf1_h, (long)D * T);

  // ---- RPB preprocessing (delta/alpha + exact kth via radix select) ----
  auto rpb_stats = [&](const float* W, long S, unsigned k, float* scal, unsigned* u,
                       unsigned* hist, float* pa, float* pb, unsigned* pc) {
    part_abssum<<<1024, 256, 0, stream>>>((const float4*)W, S / 4, pa);
    fin_abssum<<<1, 256, 0, stream>>>(pa, 1024, S, scal);
    part_kept<<<1024, 256, 0, stream>>>(W, S, scal, pb, pc);
    fin_kept<<<1, 256, 0, stream>>>(pb, pc, 1024, scal, u, k, hist);
    for (int r = 0; r < 4; ++r) {
      hist_pass<<<1024, 256, 0, stream>>>(W, S, scal, u, hist, 24 - 8 * r);
      sel_pass<<<1, 256, 0, stream>>>(hist, u, 24 - 8 * r, r == 3 ? 1 : 0);
    }
  };
  const long S1 = (long)D * T, S2 = (long)D * D;
  rpb_stats(Wq1, S1, (unsigned)(S1 / 10), scal1, u1, hist1, pa1, pb1, pc1);
  write_rpb<<<1024, 256, 0, stream>>>(Wq1, S1, scal1, u1, wq1_h);
  rpb_stats(Wq2, S2, (unsigned)(S2 / 10), scal2, u2, hist2, pa2, pb2, pc2);
  write_rpb_scaled<<<512, 256, 0, stream>>>(Wq2, D, D, scal2, u2, mixp, w2_h, 2048, 0);
  conv_scaled<<<512, 256, 0, stream>>>(Wf2, D, D, mixp, w2_h, 2048, 1024);
  mk_bias2<<<4, 256, 0, stream>>>(bq2, bf2, mixp, b2, D);

  // ---- GEMMs ----
  dim3 g(8, 64);
  // projections -> concat (+route) at column offsets 0 / 1024 / 2048
  gemm_bt<0><<<g, 256, 0, stream>>>(xv_h, wv_h, bv, concat_h, routed_h, nullptr, Kv, T, 0);
  gemm_bt<0><<<g, 256, 0, stream>>>(xt_h, wt_h, bt, concat_h, routed_h, nullptr, Kt, T, 1024);
  gemm_bt<0><<<g, 256, 0, stream>>>(xa_h, wa_h, ba, concat_h, routed_h, nullptr, Ka, T, 2048);
  // hidden layers -> A2 = [h | g], ld 2048
  gemm_bt<1><<<g, 256, 0, stream>>>(routed_h, wq1_h, bq1, a2_h, nullptr, nullptr, T, 2048, 0);
  gemm_bt<1><<<g, 256, 0, stream>>>(concat_h, wf1_h, bf1, a2_h, nullptr, nullptr, T, 2048, 1024);
  // fused output: A2 @ [mix*Wq2' | (1-mix)*Wf2]^T + (mix*bq2 + (1-mix)*bf2)
  gemm_bt<2><<<g, 256, 0, stream>>>(a2_h, w2_h, b2, nullptr, nullptr, (float*)d_out, 2048, 1024, 0);
}

// Round 2
// 574.614 us; speedup vs baseline: 1.0981x; 1.0981x over previous
//
#include <hip/hip_runtime.h>

// ---------------------------------------------------------------------------
// MultimodalFusion: fused 3-dispatch fp16 MFMA GEMMs (256-wide tiles, 2-phase
// double-buffered global_load_lds) + RPB weight preprocessing.
// ---------------------------------------------------------------------------

typedef _Float16 f16x8 __attribute__((ext_vector_type(8)));
typedef float f32x4 __attribute__((ext_vector_type(4)));

__device__ __forceinline__ unsigned short f16b(float v) {
  union { _Float16 h; unsigned short u; } cv; cv.h = (_Float16)v; return cv.u;
}

__device__ __forceinline__ void load_lds16(const void* g, void* l) {
  __builtin_amdgcn_global_load_lds(
      (const __attribute__((address_space(1))) void*)g,
      (__attribute__((address_space(3))) void*)l, 16, 0, 0);
}

__device__ __forceinline__ float sigmoidf_dev(float x) {
  return 1.0f / (1.0f + expf(-x));
}

// ---------------- preprocessing: f32 -> f16 conversion ----------------------
__global__ void f2h(const float* __restrict__ in, unsigned short* __restrict__ out, long n) {
  long n4 = n >> 2;
  for (long i = (long)blockIdx.x * blockDim.x + threadIdx.x; i < n4;
       i += (long)gridDim.x * blockDim.x) {
    float4 v = ((const float4*)in)[i];
    ushort4 o;
    o.x = f16b(v.x); o.y = f16b(v.y); o.z = f16b(v.z); o.w = f16b(v.w);
    ((ushort4*)out)[i] = o;
  }
}

// Wf2 * (1-mix) into W2[:, col0:col0+cols]
__global__ void conv_scaled(const float* __restrict__ W, int rows, int cols,
                            const float* __restrict__ mixp,
                            unsigned short* __restrict__ out, int ldd, int col0) {
  float s = 1.0f - sigmoidf_dev(mixp[0]);
  long S = (long)rows * cols;
  for (long i = (long)blockIdx.x * blockDim.x + threadIdx.x; i < S;
       i += (long)gridDim.x * blockDim.x) {
    int r = (int)(i / cols), c = (int)(i % cols);
    out[(long)r * ldd + col0 + c] = f16b(s * W[i]);
  }
}

__global__ void mk_bias2(const float* __restrict__ bq2, const float* __restrict__ bf2,
                         const float* __restrict__ mixp, float* __restrict__ b2, int n) {
  int i = blockIdx.x * blockDim.x + threadIdx.x;
  if (i < n) {
    float mix = sigmoidf_dev(mixp[0]);
    b2[i] = mix * bq2[i] + (1.0f - mix) * bf2[i];
  }
}

// ---------------- RPB stats: deterministic reductions -----------------------
__global__ void part_abssum(const float4* __restrict__ W4, long n4, float* __restrict__ part) {
  __shared__ float s[256];
  float acc = 0.f;
  for (long i = (long)blockIdx.x * blockDim.x + threadIdx.x; i < n4;
       i += (long)gridDim.x * blockDim.x) {
    float4 v = W4[i];
    acc += fabsf(v.x) + fabsf(v.y) + fabsf(v.z) + fabsf(v.w);
  }
  s[threadIdx.x] = acc; __syncthreads();
  for (int o = 128; o > 0; o >>= 1) {
    if ((int)threadIdx.x < o) s[threadIdx.x] += s[threadIdx.x + o];
    __syncthreads();
  }
  if (threadIdx.x == 0) part[blockIdx.x] = s[0];
}

__global__ void fin_abssum(const float* __restrict__ part, int np, long S,
                           float* __restrict__ scal) {
  __shared__ float s[256];
  float a = 0.f;
  for (int i = threadIdx.x; i < np; i += 256) a += part[i];
  s[threadIdx.x] = a; __syncthreads();
  for (int o = 128; o > 0; o >>= 1) {
    if ((int)threadIdx.x < o) s[threadIdx.x] += s[threadIdx.x + o];
    __syncthreads();
  }
  if (threadIdx.x == 0) scal[0] = 0.7f * (s[0] / (float)S);  // delta
}

__global__ void part_kept(const float* __restrict__ W, long S, const float* __restrict__ scal,
                          float* __restrict__ pb, unsigned* __restrict__ pc) {
  __shared__ float sf[256]; __shared__ unsigned sc[256];
  float delta = scal[0];
  float a = 0.f; unsigned c = 0;
  for (long i = (long)blockIdx.x * blockDim.x + threadIdx.x; i < S;
       i += (long)gridDim.x * blockDim.x) {
    float aw = fabsf(W[i]);
    if (aw > delta) { a += aw; ++c; }
  }
  sf[threadIdx.x] = a; sc[threadIdx.x] = c; __syncthreads();
  for (int o = 128; o > 0; o >>= 1) {
    if ((int)threadIdx.x < o) { sf[threadIdx.x] += sf[threadIdx.x + o]; sc[threadIdx.x] += sc[threadIdx.x + o]; }
    __syncthreads();
  }
  if (threadIdx.x == 0) { pb[blockIdx.x] = sf[0]; pc[blockIdx.x] = sc[0]; }
}

__global__ void fin_kept(const float* __restrict__ pb, const unsigned* __restrict__ pc, int np,
                         float* __restrict__ scal, unsigned* __restrict__ u, unsigned k,
                         unsigned* __restrict__ hist) {
  __shared__ float sf[256]; __shared__ unsigned sc[256];
  float a = 0.f; unsigned c = 0;
  for (int i = threadIdx.x; i < np; i += 256) { a += pb[i]; c += pc[i]; }
  sf[threadIdx.x] = a; sc[threadIdx.x] = c; __syncthreads();
  for (int o = 128; o > 0; o >>= 1) {
    if ((int)threadIdx.x < o) { sf[threadIdx.x] += sf[threadIdx.x + o]; sc[threadIdx.x] += sc[threadIdx.x + o]; }
    __syncthreads();
  }
  if (threadIdx.x == 0) {
    float cnt = (float)sc[0]; if (cnt < 1.f) cnt = 1.f;
    scal[1] = sf[0] / cnt;  // alpha
    u[0] = 0;               // prefix
    u[1] = k;               // k remaining
  }
  hist[threadIdx.x] = 0;
}

// ---------------- radix select of kth largest |res| -------------------------
__global__ void hist_pass(const float* __restrict__ W, long S, const float* __restrict__ scal,
                          const unsigned* __restrict__ u, unsigned* __restrict__ hist, int shift) {
  __shared__ unsigned h[256];
  h[threadIdx.x] = 0; __syncthreads();
  float delta = scal[0], alpha = scal[1];
  unsigned prefix = u[0];
  int hs = shift + 8;
  for (long i = (long)blockIdx.x * blockDim.x + threadIdx.x; i < S;
       i += (long)gridDim.x * blockDim.x) {
    float w = W[i];
    float aw = fabsf(w);
    float wq = (aw > delta) ? copysignf(alpha, w) : 0.0f;
    unsigned ub = __float_as_uint(fabsf(w - wq));
    bool ok = (hs >= 32) || ((ub >> hs) == (prefix >> hs));
    if (ok) atomicAdd(&h[(ub >> shift) & 255u], 1u);
  }
  __syncthreads();
  if (h[threadIdx.x]) atomicAdd(&hist[threadIdx.x], h[threadIdx.x]);
}

__global__ void sel_pass(unsigned* __restrict__ hist, unsigned* __restrict__ u, int shift, int last) {
  __shared__ unsigned h[256];
  int t = threadIdx.x;
  h[t] = hist[t];
  __syncthreads();
  if (t == 0) {
    unsigned krem = u[1];
    unsigned cum = 0, above = 0;
    int bstar = 0;
    for (int b = 255; b >= 0; --b) {
      unsigned nc = cum + h[b];
      if (nc >= krem) { bstar = b; above = cum; break; }
      cum = nc;
    }
    u[0] |= ((unsigned)bstar) << shift;
    u[1] = krem - above;
    if (last) u[2] = u[0];  // kth value bit pattern
  }
  __syncthreads();
  hist[t] = 0;
}

// ---------------- RPB weight writers -----------------------------------------
__global__ void write_rpb(const float* __restrict__ W, long S, const float* __restrict__ scal,
                          const unsigned* __restrict__ u, unsigned short* __restrict__ out) {
  float delta = scal[0], alpha = scal[1];
  unsigned kth = u[2];
  for (long i = (long)blockIdx.x * blockDim.x + threadIdx.x; i < S;
       i += (long)gridDim.x * blockDim.x) {
    float w = W[i];
    float aw = fabsf(w);
    float wq = (aw > delta) ? copysignf(alpha, w) : 0.0f;
    float res = w - wq;
    unsigned ub = __float_as_uint(fabsf(res));
    float v = wq + ((ub >= kth) ? res : 0.0f);
    out[i] = f16b(v);
  }
}

__global__ void write_rpb_scaled(const float* __restrict__ W, int rows, int cols,
                                 const float* __restrict__ scal, const unsigned* __restrict__ u,
                                 const float* __restrict__ mixp,
                                 unsigned short* __restrict__ out, int ldd, int col0) {
  float delta = scal[0], alpha = scal[1];
  unsigned kth = u[2];
  float mix = sigmoidf_dev(mixp[0]);
  long S = (long)rows * cols;
  for (long i = (long)blockIdx.x * blockDim.x + threadIdx.x; i < S;
       i += (long)gridDim.x * blockDim.x) {
    int r = (int)(i / cols), c = (int)(i % cols);
    float w = W[i];
    float aw = fabsf(w);
    float wq = (aw > delta) ? copysignf(alpha, w) : 0.0f;
    float res = w - wq;
    unsigned ub = __float_as_uint(fabsf(res));
    float v = wq + ((ub >= kth) ? res : 0.0f);
    out[(long)r * ldd + col0 + c] = f16b(mix * v);
  }
}

// ---------------- fused GEMM: C[M,sel-cols] = A_sel @ B_sel^T + bias ---------
// BM x 256 tile, BK=64, 512 threads = 8 waves (2 x 4). Per-wave (BM/2) x 64.
// Per 256-col block c: sel = c>>2 picks operand set, lc = c&3 picks the
// 256-row slice of that B / bias. EPI 0: concat+route, 1: relu, 2: f32 out.
struct GemmArgs {
  const unsigned short* A0; const unsigned short* A1; const unsigned short* A2;
  const unsigned short* B0; const unsigned short* B1; const unsigned short* B2;
  const float* c0; const float* c1; const float* c2;
  int K0, K1, K2;
  int nrows;   // grid rows = M / BM
  int ldc;     // output leading dim
  unsigned short* o0; unsigned short* o1; float* oF;
};

template <int BM, int EPI>
__global__ __launch_bounds__(512) void gemm2(GemmArgs g) {
  constexpr int BN = 256, BK = 64;
  constexpr int RW = BM / 2;       // per-wave rows
  constexpr int MR = RW / 16;      // fragment repeats in M (8 or 4)
  constexpr int AL = BM * BK * 2;  // A tile bytes (32768 / 16384)
  constexpr int BL = BN * BK * 2;  // 32768
  constexpr int AISS = AL / 8192;  // global_load_lds issues for A (4 / 2)
  extern __shared__ __align__(16) char sm[];

  const int tid = threadIdx.x, wid = tid >> 6, lane = tid & 63;
  const int wm = wid >> 2, wn = wid & 3;

  // bijective XCD-chunked swizzle (nwg % 8 == 0), row-fastest inside chunk:
  // each XCD owns contiguous rows of ~1 col-block -> B panel stays L2-hot.
  const int nwg = gridDim.x;
  const int id = (blockIdx.x & 7) * (nwg >> 3) + (blockIdx.x >> 3);
  const int r = id % g.nrows, c = id / g.nrows;
  const int sel = c >> 2, lc = c & 3;

  const unsigned short* A = sel == 0 ? g.A0 : (sel == 1 ? g.A1 : g.A2);
  const unsigned short* Bw = sel == 0 ? g.B0 : (sel == 1 ? g.B1 : g.B2);
  const float* bias = sel == 0 ? g.c0 : (sel == 1 ? g.c1 : g.c2);
  const int K = sel == 0 ? g.K0 : (sel == 1 ? g.K1 : g.K2);
  const long brow = (long)r * BM;

  f32x4 acc[MR][4];
#pragma unroll
  for (int m = 0; m < MR; ++m)
#pragma unroll
    for (int n = 0; n < 4; ++n)
#pragma unroll
      for (int e = 0; e < 4; ++e) acc[m][n][e] = 0.f;

  // staging source pointers (per-lane); LDS dest = uniform base + lane*16
  const unsigned short* aSrc[AISS];
#pragma unroll
  for (int j = 0; j < AISS; ++j) {
    int o = j * 8192 + wid * 1024 + lane * 16;
    int row = o >> 7, colb = o & 127;
    aSrc[j] = A + (brow + row) * (long)K + (colb >> 1);
  }
  const unsigned short* bSrc[4];
#pragma unroll
  for (int j = 0; j < 4; ++j) {
    int o = j * 8192 + wid * 1024 + lane * 16;
    int row = o >> 7, colb = o & 127;
    bSrc[j] = Bw + (long)(lc * 256 + row) * K + (colb >> 1);
  }

  auto STAGE = [&](int buf, int k0) {
    char* lAp = sm + (size_t)buf * AL;
    char* lBp = sm + 2 * AL + (size_t)buf * BL;
#pragma unroll
    for (int j = 0; j < AISS; ++j)
      load_lds16(aSrc[j] + k0, lAp + j * 8192 + wid * 1024);
#pragma unroll
    for (int j = 0; j < 4; ++j)
      load_lds16(bSrc[j] + k0, lBp + j * 8192 + wid * 1024);
  };

  auto COMPUTE = [&](int buf) {
    const char* lAp = sm + (size_t)buf * AL;
    const char* lBp = sm + 2 * AL + (size_t)buf * BL;
#pragma unroll
    for (int kk = 0; kk < 2; ++kk) {
      const int kb = (lane >> 4) * 16 + kk * 64;
      f16x8 a[MR], b[4];
#pragma unroll
      for (int m = 0; m < MR; ++m)
        a[m] = *(const f16x8*)(lAp + (wm * RW + m * 16 + (lane & 15)) * 128 + kb);
#pragma unroll
      for (int n = 0; n < 4; ++n)
        b[n] = *(const f16x8*)(lBp + (wn * 64 + n * 16 + (lane & 15)) * 128 + kb);
#pragma unroll
      for (int m = 0; m < MR; ++m)
#pragma unroll
        for (int n = 0; n < 4; ++n)
          acc[m][n] = __builtin_amdgcn_mfma_f32_16x16x32_f16(a[m], b[n], acc[m][n], 0, 0, 0);
    }
  };

  const int NT = K >> 6;
  STAGE(0, 0);
  __syncthreads();  // drains vmcnt(0): tile 0 landed
  int cur = 0;
  for (int t = 0; t < NT - 1; ++t) {
    STAGE(cur ^ 1, (t + 1) << 6);  // prefetch next tile while computing
    COMPUTE(cur);
    __syncthreads();  // vmcnt(0)+lgkmcnt(0)+barrier: next tile ready, buf free
    cur ^= 1;
  }
  COMPUTE(cur);

  // epilogue: C row = base + m*16 + (lane>>4)*4 + e, col = base + n*16 + (lane&15)
  const int cb = c * BN + wn * 64;
  const int rb = r * BM + wm * RW;
  const int bcol0 = lc * 256 + wn * 64;
#pragma unroll
  for (int m = 0; m < MR; ++m) {
    int r0 = rb + m * 16 + ((lane >> 4) << 2);
#pragma unroll
    for (int n = 0; n < 4; ++n) {
      int ccol = cb + n * 16 + (lane & 15);
      float bb = bias[bcol0 + n * 16 + (lane & 15)];
#pragma unroll
      for (int e = 0; e < 4; ++e) {
        float v = acc[m][n][e] + bb;
        long idx = (long)(r0 + e) * g.ldc + ccol;
        if constexpr (EPI == 0) {
          g.o0[idx] = f16b(v);
          g.o1[idx] = f16b(fabsf(v) >= 0.05f ? v : 0.0f);
        } else if constexpr (EPI == 1) {
          g.o0[idx] = f16b(fmaxf(v, 0.0f));
        } else {
          g.oF[idx] = v;
        }
      }
    }
  }
}

// ---------------------------------------------------------------------------
extern "C" void kernel_launch(void* const* d_in, const int* in_sizes, int n_in,
                              void* d_out, int out_size, void* d_ws, size_t ws_size,
                              hipStream_t stream) {
  const float* xv = (const float*)d_in[0];
  const float* xt = (const float*)d_in[1];
  const float* xa = (const float*)d_in[2];
  const float* Wv = (const float*)d_in[3];
  const float* bv = (const float*)d_in[4];
  const float* Wt = (const float*)d_in[5];
  const float* bt = (const float*)d_in[6];
  const float* Wa = (const float*)d_in[7];
  const float* ba = (const float*)d_in[8];
  const float* Wq1 = (const float*)d_in[9];
  const float* bq1 = (const float*)d_in[10];
  const float* Wq2 = (const float*)d_in[11];
  const float* bq2 = (const float*)d_in[12];
  const float* Wf1 = (const float*)d_in[13];
  const float* bf1 = (const float*)d_in[14];
  const float* Wf2 = (const float*)d_in[15];
  const float* bf2 = (const float*)d_in[16];
  const float* mixp = (const float*)d_in[17];

  const int B = 8192, D = 1024, T = 3072;
  const int Kv = 2048, Kt = 1024, Ka = 512;

  char* w = (char*)d_ws;
  auto alloc = [&](size_t bytes) -> char* {
    char* p = w; w += (bytes + 255) & ~(size_t)255; return p;
  };
  unsigned short* xv_h = (unsigned short*)alloc((size_t)B * Kv * 2);
  unsigned short* xt_h = (unsigned short*)alloc((size_t)B * Kt * 2);
  unsigned short* xa_h = (unsigned short*)alloc((size_t)B * Ka * 2);
  unsigned short* wv_h = (unsigned short*)alloc((size_t)D * Kv * 2);
  unsigned short* wt_h = (unsigned short*)alloc((size_t)D * Kt * 2);
  unsigned short* wa_h = (unsigned short*)alloc((size_t)D * Ka * 2);
  unsigned short* wq1_h = (unsigned short*)alloc((size_t)D * T * 2);
  unsigned short* wf1_h = (unsigned short*)alloc((size_t)D * T * 2);
  unsigned short* w2_h = (unsigned short*)alloc((size_t)D * 2048 * 2);
  unsigned short* concat_h = (unsigned short*)alloc((size_t)B * T * 2);
  unsigned short* routed_h = (unsigned short*)alloc((size_t)B * T * 2);
  unsigned short* a2_h = (unsigned short*)alloc((size_t)B * 2048 * 2);
  float* b2 = (float*)alloc(D * 4);
  float* scal1 = (float*)alloc(64);
  unsigned* u1 = (unsigned*)alloc(64);
  unsigned* hist1 = (unsigned*)alloc(1024);
  float* pa1 = (float*)alloc(1024 * 4);
  float* pb1 = (float*)alloc(1024 * 4);
  unsigned* pc1 = (unsigned*)alloc(1024 * 4);
  float* scal2 = (float*)alloc(64);
  unsigned* u2 = (unsigned*)alloc(64);
  unsigned* hist2 = (unsigned*)alloc(1024);
  float* pa2 = (float*)alloc(1024 * 4);
  float* pb2 = (float*)alloc(1024 * 4);
  unsigned* pc2 = (unsigned*)alloc(1024 * 4);

  // ---- conversions to fp16 ----
  f2h<<<2048, 256, 0, stream>>>(xv, xv_h, (long)B * Kv);
  f2h<<<1024, 256, 0, stream>>>(xt, xt_h, (long)B * Kt);
  f2h<<<512, 256, 0, stream>>>(xa, xa_h, (long)B * Ka);
  f2h<<<256, 256, 0, stream>>>(Wv, wv_h, (long)D * Kv);
  f2h<<<128, 256, 0, stream>>>(Wt, wt_h, (long)D * Kt);
  f2h<<<64, 256, 0, stream>>>(Wa, wa_h, (long)D * Ka);
  f2h<<<512, 256, 0, stream>>>(Wf1, wf1_h, (long)D * T);

  // ---- RPB preprocessing (delta/alpha + exact kth via radix select) ----
  auto rpb_stats = [&](const float* W, long S, unsigned k, float* scal, unsigned* u,
                       unsigned* hist, float* pa, float* pb, unsigned* pc) {
    part_abssum<<<1024, 256, 0, stream>>>((const float4*)W, S / 4, pa);
    fin_abssum<<<1, 256, 0, stream>>>(pa, 1024, S, scal);
    part_kept<<<1024, 256, 0, stream>>>(W, S, scal, pb, pc);
    fin_kept<<<1, 256, 0, stream>>>(pb, pc, 1024, scal, u, k, hist);
    for (int r = 0; r < 4; ++r) {
      hist_pass<<<1024, 256, 0, stream>>>(W, S, scal, u, hist, 24 - 8 * r);
      sel_pass<<<1, 256, 0, stream>>>(hist, u, 24 - 8 * r, r == 3 ? 1 : 0);
    }
  };
  const long S1 = (long)D * T, S2 = (long)D * D;
  rpb_stats(Wq1, S1, (unsigned)(S1 / 10), scal1, u1, hist1, pa1, pb1, pc1);
  write_rpb<<<1024, 256, 0, stream>>>(Wq1, S1, scal1, u1, wq1_h);
  rpb_stats(Wq2, S2, (unsigned)(S2 / 10), scal2, u2, hist2, pa2, pb2, pc2);
  write_rpb_scaled<<<512, 256, 0, stream>>>(Wq2, D, D, scal2, u2, mixp, w2_h, 2048, 0);
  conv_scaled<<<512, 256, 0, stream>>>(Wf2, D, D, mixp, w2_h, 2048, 1024);
  mk_bias2<<<4, 256, 0, stream>>>(bq2, bf2, mixp, b2, D);

  // ---- fused GEMMs (3 dispatches) ----
  (void)hipFuncSetAttribute((const void*)&gemm2<256, 0>,
                            hipFuncAttributeMaxDynamicSharedMemorySize, 131072);
  (void)hipFuncSetAttribute((const void*)&gemm2<256, 1>,
                            hipFuncAttributeMaxDynamicSharedMemorySize, 131072);
  (void)hipFuncSetAttribute((const void*)&gemm2<128, 2>,
                            hipFuncAttributeMaxDynamicSharedMemorySize, 131072);

  // projections -> concat (+route): N = 3072, col-blocks 0-3 v, 4-7 t, 8-11 a
  GemmArgs gp;
  gp.A0 = xv_h; gp.A1 = xt_h; gp.A2 = xa_h;
  gp.B0 = wv_h; gp.B1 = wt_h; gp.B2 = wa_h;
  gp.c0 = bv; gp.c1 = bt; gp.c2 = ba;
  gp.K0 = Kv; gp.K1 = Kt; gp.K2 = Ka;
  gp.nrows = B / 256; gp.ldc = T;
  gp.o0 = concat_h; gp.o1 = routed_h; gp.oF = nullptr;
  gemm2<256, 0><<<12 * (B / 256), 512, 131072, stream>>>(gp);

  // hidden -> A2 = [h | g]: N = 2048, col-blocks 0-3 quant, 4-7 full
  GemmArgs gh;
  gh.A0 = routed_h; gh.A1 = concat_h; gh.A2 = routed_h;
  gh.B0 = wq1_h; gh.B1 = wf1_h; gh.B2 = wq1_h;
  gh.c0 = bq1; gh.c1 = bf1; gh.c2 = bq1;
  gh.K0 = T; gh.K1 = T; gh.K2 = T;
  gh.nrows = B / 256; gh.ldc = 2048;
  gh.o0 = a2_h; gh.o1 = nullptr; gh.oF = nullptr;
  gemm2<256, 1><<<8 * (B / 256), 512, 131072, stream>>>(gh);

  // fused output: A2 @ [mix*Wq2' | (1-mix)*Wf2]^T + mixed bias, 128x256 tile
  GemmArgs gf;
  gf.A0 = a2_h; gf.A1 = a2_h; gf.A2 = a2_h;
  gf.B0 = w2_h; gf.B1 = w2_h; gf.B2 = w2_h;
  gf.c0 = b2; gf.c1 = b2; gf.c2 = b2;
  gf.K0 = 2048; gf.K1 = 2048; gf.K2 = 2048;
  gf.nrows = B / 128; gf.ldc = D;
  gf.o0 = nullptr; gf.o1 = nullptr; gf.oF = (float*)d_out;
  gemm2<128, 2><<<4 * (B / 128), 512, 98304, stream>>>(gf);
}